// Round 1
// baseline (2409.644 us; speedup 1.0000x reference)
//
#include <hip/hip_runtime.h>

#define B_ 2048
#define T_ 200
#define D_ 128
#define H1_ 256
#define H2_ 128
#define TB 8

__device__ __forceinline__ float sigf(float x) {
  return 1.0f / (1.0f + __expf(-x));
}

__global__ __launch_bounds__(256, 1)
void attn_kernel(const float* __restrict__ query,
                 const float* __restrict__ keys,
                 const int*   __restrict__ mask,
                 const float* __restrict__ W1,
                 const float* __restrict__ b1,
                 const float* __restrict__ W2,
                 const float* __restrict__ b2,
                 const float* __restrict__ W3,
                 const float* __restrict__ b3,
                 float* __restrict__ out)
{
  // LDS: 128K + 4K + 8K + 4K + small = ~146 KB (gfx950 has 160 KB/CU)
  __shared__ float WqL[D_ * H1_];      // fused layer-1 weight for this b
  __shared__ float kbuf[TB][D_];
  __shared__ float h1buf[TB][H1_];
  __shared__ float h2buf[TB][H2_];
  __shared__ float qL[D_];
  __shared__ float qbL[H1_];
  __shared__ float w3L[H2_];
  __shared__ float ebuf[TB];

  const int b = blockIdx.x;
  const int tid = threadIdx.x;

  if (tid < D_) {
    qL[tid]  = query[(size_t)b * D_ + tid];
    w3L[tid] = W3[tid];
  }
  __syncthreads();

  // qb[h] = b1[h] + sum_d q_d * (W1[128+d][h] - W1[256+d][h])
  {
    float acc = b1[tid];
#pragma unroll 8
    for (int d = 0; d < D_; ++d) {
      acc += qL[d] * (W1[(128 + d) * H1_ + tid] - W1[(256 + d) * H1_ + tid]);
    }
    qbL[tid] = acc;
  }
  // Wq[d][h] = W1[d][h] + W1[256+d][h] + q_d * W1[384+d][h]
#pragma unroll 4
  for (int d = 0; d < D_; ++d) {
    WqL[d * H1_ + tid] = W1[d * H1_ + tid] + W1[(256 + d) * H1_ + tid]
                       + qL[d] * W1[(384 + d) * H1_ + tid];
  }
  __syncthreads();

  const int hq = tid & 63;   // layer1: 4 consecutive h = hq*4
  const int jp = tid >> 6;   // wave id 0..3 -> rows {jp, jp+4}
  const int ko = tid & 127;  // layer2: output col
  const int g2 = tid >> 7;   // 0/1 -> rows {g2, g2+2, g2+4, g2+6}

  float numacc = 0.0f;       // per-thread output accumulator (d = ko, half g2)
  float den = 0.0f;
  const float bias3 = b3[0];
  const float bias2 = b2[ko];

  for (int t0 = 0; t0 < T_; t0 += TB) {
    __syncthreads();  // prev num/den phase done with kbuf
    {
      const int row = tid >> 5, c4 = (tid & 31) * 4;
      const float4 kv = *(const float4*)(keys + ((size_t)b * T_ + t0 + row) * D_ + c4);
      *(float4*)&kbuf[row][c4] = kv;
    }
    __syncthreads();

    // ---- layer 1: h1[j][h] = sig(qb[h] + sum_d kbuf[j][d]*Wq[d][h]) ----
    {
      float4 acc0 = {0,0,0,0}, acc1 = {0,0,0,0};
      const float4* Wq4 = (const float4*)WqL;
#pragma unroll 4
      for (int d = 0; d < D_; ++d) {
        const float4 wq = Wq4[d * 64 + hq];
        const float k0 = kbuf[jp][d];
        const float k1 = kbuf[jp + 4][d];
        acc0.x += k0 * wq.x; acc0.y += k0 * wq.y; acc0.z += k0 * wq.z; acc0.w += k0 * wq.w;
        acc1.x += k1 * wq.x; acc1.y += k1 * wq.y; acc1.z += k1 * wq.z; acc1.w += k1 * wq.w;
      }
      const float4 qb4 = ((const float4*)qbL)[hq];
      float4 o0, o1;
      o0.x = sigf(qb4.x + acc0.x); o0.y = sigf(qb4.y + acc0.y);
      o0.z = sigf(qb4.z + acc0.z); o0.w = sigf(qb4.w + acc0.w);
      o1.x = sigf(qb4.x + acc1.x); o1.y = sigf(qb4.y + acc1.y);
      o1.z = sigf(qb4.z + acc1.z); o1.w = sigf(qb4.w + acc1.w);
      ((float4*)&h1buf[jp][0])[hq]     = o0;
      ((float4*)&h1buf[jp + 4][0])[hq] = o1;
    }
    __syncthreads();

    // ---- layer 2: h2[j][k] = sig(b2[k] + sum_dd h1[j][dd]*W2[dd][k]) ----
    {
      float acc[4] = {0,0,0,0};
#pragma unroll 4
      for (int dd = 0; dd < H1_; ++dd) {
        const float w2 = W2[dd * H2_ + ko];
        acc[0] += h1buf[g2 + 0][dd] * w2;
        acc[1] += h1buf[g2 + 2][dd] * w2;
        acc[2] += h1buf[g2 + 4][dd] * w2;
        acc[3] += h1buf[g2 + 6][dd] * w2;
      }
#pragma unroll
      for (int jj = 0; jj < 4; ++jj)
        h2buf[g2 + 2 * jj][ko] = sigf(acc[jj] + bias2);
    }
    __syncthreads();

    // ---- layer 3 + mask: e[j] = mask ? exp(sig(h2[j].W3 + b3)) : 0 ----
    {
      const int j3 = tid >> 5, l5 = tid & 31;
      float p = 0.0f;
#pragma unroll
      for (int i = 0; i < 4; ++i)
        p += h2buf[j3][l5 + 32 * i] * w3L[l5 + 32 * i];
#pragma unroll
      for (int off = 16; off > 0; off >>= 1)
        p += __shfl_xor(p, off);
      if (l5 == 0) {
        const float sc = sigf(p + bias3);
        const int m = mask[(size_t)b * T_ + t0 + j3];
        ebuf[j3] = (m == 1) ? __expf(sc) : 0.0f;
      }
    }
    __syncthreads();

    // ---- online accumulate: num[d] += e[j]*k[j][d], den += e[j] ----
    {
      float e[TB];
#pragma unroll
      for (int j = 0; j < TB; ++j) { e[j] = ebuf[j]; den += e[j]; }
      float s = 0.0f;
#pragma unroll
      for (int jj = 0; jj < 4; ++jj)
        s += e[g2 * 4 + jj] * kbuf[g2 * 4 + jj][ko];
      numacc += s;
    }
  }

  __syncthreads();
  if (g2 == 1) h1buf[0][ko] = numacc;
  __syncthreads();
  if (g2 == 0) out[(size_t)b * D_ + ko] = (numacc + h1buf[0][ko]) / den;
}

extern "C" void kernel_launch(void* const* d_in, const int* in_sizes, int n_in,
                              void* d_out, int out_size, void* d_ws, size_t ws_size,
                              hipStream_t stream) {
  const float* query = (const float*)d_in[0];
  const float* keys  = (const float*)d_in[1];
  const int*   mask  = (const int*)  d_in[2];
  const float* W1    = (const float*)d_in[3];
  const float* b1    = (const float*)d_in[4];
  const float* W2    = (const float*)d_in[5];
  const float* b2    = (const float*)d_in[6];
  const float* W3    = (const float*)d_in[7];
  const float* b3    = (const float*)d_in[8];
  float* out = (float*)d_out;

  attn_kernel<<<B_, 256, 0, stream>>>(query, keys, mask, W1, b1, W2, b2, W3, b3, out);
}

// Round 2
// 800.959 us; speedup vs baseline: 3.0084x; 3.0084x over previous
//
#include <hip/hip_runtime.h>

#define B_  2048
#define T_  200
#define D_  128
#define H1_ 256
#define H2_ 128

typedef __attribute__((ext_vector_type(8))) short  s16x8;
typedef __attribute__((ext_vector_type(4))) float  f32x4;

// ws layout (bytes)
#define WS_WCF   0         // bf16 Wc frags: 256x256 -> 131072 B
#define WS_W2F   131072    // bf16 W2 frags: 256x128 -> 65536 B
#define WS_Q2    196608    // f32 (W1b - W1c): 128x256 -> 131072 B
#define WS_QB    327680    // f32 qb: 2048x256 -> 2097152 B

__device__ __forceinline__ unsigned short f2bf(float f) {
  union { float f; unsigned u; } v; v.f = f;
  unsigned r = v.u + 0x7fffu + ((v.u >> 16) & 1u);
  return (unsigned short)(r >> 16);
}
__device__ __forceinline__ float bf2f(unsigned short u) {
  union { unsigned u; float f; } v; v.u = ((unsigned)u) << 16;
  return v.f;
}
__device__ __forceinline__ float sigf(float x) {
  return __builtin_amdgcn_rcpf(1.0f + __expf(-x));
}

// ---------------- prep: weight fragments + Q2 ----------------
__global__ __launch_bounds__(256)
void prep_weights(const float* __restrict__ W1, const float* __restrict__ W2,
                  unsigned short* __restrict__ wcf, unsigned short* __restrict__ w2f,
                  float* __restrict__ Q2)
{
  int g = blockIdx.x * 256 + threadIdx.x;
  if (g < 8192) {
    // Wc frag: c in [0,16), s in [0,8), l in [0,64)
    int c = g >> 9, s = (g >> 6) & 7, l = g & 63;
    int col = 16 * c + (l & 15);
#pragma unroll
    for (int j = 0; j < 8; ++j) {
      int k = 32 * s + 8 * (l >> 4) + j;
      float v = W1[(256 + k) * H1_ + col];          // W1c (k<128) or W1d (k>=128)
      if (k < 128) v += W1[k * H1_ + col];          // + W1a
      wcf[(size_t)g * 8 + j] = f2bf(v);
    }
  } else if (g < 12288) {
    int g2 = g - 8192;                              // c in [0,8), s in [0,8), l
    int c = g2 >> 9, s = (g2 >> 6) & 7, l = g2 & 63;
    int col = 16 * c + (l & 15);
#pragma unroll
    for (int j = 0; j < 8; ++j) {
      int k = 32 * s + 8 * (l >> 4) + j;
      w2f[(size_t)g2 * 8 + j] = f2bf(W2[k * H2_ + col]);
    }
  } else {
    int g3 = g - 12288;                             // 8192 float4 tasks over 128x256
    int e = g3 * 4;
    int d = e >> 8, h = e & 255;
#pragma unroll
    for (int j = 0; j < 4; ++j)
      Q2[e + j] = W1[(128 + d) * H1_ + h + j] - W1[(256 + d) * H1_ + h + j];
  }
}

// ---------------- prep: qb[b][h] = b1[h] + q[b] @ Q2 ----------------
__global__ __launch_bounds__(256)
void qb_prep(const float* __restrict__ query, const float* __restrict__ b1,
             const float* __restrict__ Q2, float* __restrict__ qb)
{
  __shared__ float q8[8 * 128];
  int b0 = blockIdx.x * 8;
  int tid = threadIdx.x;
  {
    const float4 v = *(const float4*)(query + (size_t)b0 * 128 + tid * 4);
    *(float4*)(q8 + tid * 4) = v;
  }
  __syncthreads();
  int h = tid;
  float acc[8];
#pragma unroll
  for (int j = 0; j < 8; ++j) acc[j] = b1[h];
  for (int d = 0; d < 128; ++d) {
    float w = Q2[d * 256 + h];
#pragma unroll
    for (int j = 0; j < 8; ++j) acc[j] += q8[j * 128 + d] * w;
  }
#pragma unroll
  for (int j = 0; j < 8; ++j) qb[(size_t)(b0 + j) * 256 + h] = acc[j];
}

// ---------------- main ----------------
__global__ __launch_bounds__(512, 4)
void attn_main(const float* __restrict__ query, const float* __restrict__ keys,
               const int* __restrict__ mask,
               const unsigned short* __restrict__ wcf,
               const unsigned short* __restrict__ w2f,
               const float* __restrict__ qb_ws,
               const float* __restrict__ b2, const float* __restrict__ W3,
               const float* __restrict__ b3, float* __restrict__ out)
{
  __shared__ __align__(16) unsigned short Xc[64 * 256];   // 32KB swizzled
  __shared__ __align__(16) unsigned short H1c[64 * 256];  // 32KB swizzled
  __shared__ float qL[128];
  __shared__ float qbL[256];
  __shared__ float scorep[64 * 8];
  __shared__ float ebuf[64];
  __shared__ float numred[4][128];
  __shared__ float denred[4];

  const int b = blockIdx.x;
  const int tid = threadIdx.x;
  const int lane = tid & 63;
  const int wid = tid >> 6;

  if (tid < 128) qL[tid] = query[(size_t)b * 128 + tid];
  if (tid < 256) qbL[tid] = qb_ws[(size_t)b * 256 + tid];
  const float b2v = b2[wid * 16 + (lane & 15)];
  const float w3v = W3[wid * 16 + (lane & 15)];
  const float b3v = b3[0];

  float numacc = 0.0f, denacc = 0.0f;
  const int rg = tid >> 7;          // row-group 0..3 (uniform per wave)
  const int dcol = tid & 127;       // output d

  __syncthreads();

  for (int ch = 0; ch < 4; ++ch) {
    __syncthreads();  // Xc free from previous accum phase

    // ---- phase 1: stage X = [k, q*k] (bf16, swizzled) ----
#pragma unroll
    for (int qq = 0; qq < 2; ++qq) {
      int p = tid * 2 + qq;
      int row = p >> 4, c = p & 15;      // c: 8-col unit within k-part
      int t = ch * 64 + row;
      float4 k0 = {0,0,0,0}, k1 = {0,0,0,0};
      if (t < T_) {
        const float* kp = keys + ((size_t)b * T_ + t) * 128 + 8 * c;
        k0 = *(const float4*)kp;
        k1 = *(const float4*)(kp + 4);
      }
      float kv[8] = {k0.x,k0.y,k0.z,k0.w,k1.x,k1.y,k1.z,k1.w};
      s16x8 xk, xq;
#pragma unroll
      for (int j = 0; j < 8; ++j) {
        xk[j] = (short)f2bf(kv[j]);
        xq[j] = (short)f2bf(kv[j] * qL[8 * c + j]);
      }
      int sw = (row & 7) << 3;
      *(s16x8*)&Xc[(row * 256 + 8 * c) ^ sw]       = xk;
      *(s16x8*)&Xc[(row * 256 + 128 + 8 * c) ^ sw] = xq;
    }
    __syncthreads();

    // ---- layer 1: h1 = sig(X @ Wc + qb) ----
#pragma unroll
    for (int pass = 0; pass < 2; ++pass) {
      int c1 = pass * 8 + wid;
      s16x8 Bf[8];
#pragma unroll
      for (int s = 0; s < 8; ++s)
        Bf[s] = *(const s16x8*)(wcf + ((size_t)(c1 * 8 + s) * 64 + lane) * 8);
      float qbv = qbL[c1 * 16 + (lane & 15)];
#pragma unroll
      for (int rt = 0; rt < 4; ++rt) {
        s16x8 Af[8];
        int arow = rt * 16 + (lane & 15);
        int abase = arow * 256 + (lane >> 4) * 8;
        int asw = (lane & 7) << 3;
#pragma unroll
        for (int s = 0; s < 8; ++s)
          Af[s] = *(const s16x8*)&Xc[(abase + s * 32) ^ asw];
        f32x4 acc = {0,0,0,0};
#pragma unroll
        for (int s = 0; s < 8; ++s)
          acc = __builtin_amdgcn_mfma_f32_16x16x32_bf16(Af[s], Bf[s], acc, 0, 0, 0);
#pragma unroll
        for (int i = 0; i < 4; ++i) {
          int row = rt * 16 + (lane >> 4) * 4 + i;
          float h = sigf(acc[i] + qbv);
          H1c[(row * 256 + c1 * 16 + (lane & 15)) ^ ((row & 7) << 3)] = f2bf(h);
        }
      }
    }
    __syncthreads();

    // ---- layer 2 + layer 3 partials ----
    {
      s16x8 Bf[8];
#pragma unroll
      for (int s = 0; s < 8; ++s)
        Bf[s] = *(const s16x8*)(w2f + ((size_t)(wid * 8 + s) * 64 + lane) * 8);
#pragma unroll
      for (int rt = 0; rt < 4; ++rt) {
        s16x8 Af[8];
        int arow = rt * 16 + (lane & 15);
        int abase = arow * 256 + (lane >> 4) * 8;
        int asw = (lane & 7) << 3;
#pragma unroll
        for (int s = 0; s < 8; ++s)
          Af[s] = *(const s16x8*)&H1c[(abase + s * 32) ^ asw];
        f32x4 acc = {0,0,0,0};
#pragma unroll
        for (int s = 0; s < 8; ++s)
          acc = __builtin_amdgcn_mfma_f32_16x16x32_bf16(Af[s], Bf[s], acc, 0, 0, 0);
        float p[4];
#pragma unroll
        for (int i = 0; i < 4; ++i)
          p[i] = sigf(acc[i] + b2v) * w3v;
#pragma unroll
        for (int m = 1; m <= 8; m <<= 1)
#pragma unroll
          for (int i = 0; i < 4; ++i)
            p[i] += __shfl_xor(p[i], m);
        if ((lane & 15) == 0) {
#pragma unroll
          for (int i = 0; i < 4; ++i) {
            int row = rt * 16 + (lane >> 4) * 4 + i;
            scorep[row * 8 + wid] = p[i];
          }
        }
      }
    }
    __syncthreads();

    // ---- finalize score -> e ----
    if (tid < 64) {
      int r = tid, t = ch * 64 + r;
      float s8 = 0.0f;
#pragma unroll
      for (int w = 0; w < 8; ++w) s8 += scorep[r * 8 + w];
      float e = 0.0f;
      if (t < T_ && mask[(size_t)b * T_ + t] == 1)
        e = __expf(sigf(s8 + b3v));
      ebuf[r] = e;
    }
    __syncthreads();

    // ---- accumulate num/den from staged keys ----
#pragma unroll 4
    for (int rr = 0; rr < 16; ++rr) {
      int row = rg * 16 + rr;
      float ev = ebuf[row];              // wave-uniform
      if (ev != 0.0f) {
        denacc += ev;
        numacc += ev * bf2f(Xc[(row * 256 + dcol) ^ ((row & 7) << 3)]);
      }
    }
  }

  // ---- final reduce across the 4 row-groups ----
  __syncthreads();
  numred[rg][dcol] = numacc;
  if ((tid & 127) == 0) denred[rg] = denacc;
  __syncthreads();
  if (tid < 128) {
    float num = numred[0][tid] + numred[1][tid] + numred[2][tid] + numred[3][tid];
    float den = denred[0] + denred[1] + denred[2] + denred[3];
    out[(size_t)b * 128 + tid] = num / den;
  }
}

extern "C" void kernel_launch(void* const* d_in, const int* in_sizes, int n_in,
                              void* d_out, int out_size, void* d_ws, size_t ws_size,
                              hipStream_t stream) {
  const float* query = (const float*)d_in[0];
  const float* keys  = (const float*)d_in[1];
  const int*   mask  = (const int*)  d_in[2];
  const float* W1    = (const float*)d_in[3];
  const float* b1    = (const float*)d_in[4];
  const float* W2    = (const float*)d_in[5];
  const float* b2    = (const float*)d_in[6];
  const float* W3    = (const float*)d_in[7];
  const float* b3    = (const float*)d_in[8];
  float* out = (float*)d_out;

  char* ws = (char*)d_ws;
  unsigned short* wcf = (unsigned short*)(ws + WS_WCF);
  unsigned short* w2f = (unsigned short*)(ws + WS_W2F);
  float*          Q2  = (float*)(ws + WS_Q2);
  float*          qb  = (float*)(ws + WS_QB);

  prep_weights<<<80, 256, 0, stream>>>(W1, W2, wcf, w2f, Q2);
  qb_prep<<<256, 256, 0, stream>>>(query, b1, Q2, qb);
  attn_main<<<B_, 512, 0, stream>>>(query, keys, mask, wcf, w2f, qb,
                                    b2, W3, b3, out);
}

// Round 3
// 246.734 us; speedup vs baseline: 9.7662x; 3.2462x over previous
//
#include <hip/hip_runtime.h>

#define B_  2048
#define T_  200
#define D_  128
#define H1_ 256
#define H2_ 128

typedef __attribute__((ext_vector_type(8))) short  s16x8;
typedef __attribute__((ext_vector_type(4))) float  f32x4;

// ws layout (bytes)
#define WS_WCF   0         // bf16 Wc frags: 256x256 -> 131072 B
#define WS_W2F   131072    // bf16 W2 frags: 256x128 -> 65536 B
#define WS_Q2    196608    // f32 (W1b - W1c): 128x256 -> 131072 B
#define WS_QB    327680    // f32 qb: 2048x256 -> 2097152 B

__device__ __forceinline__ unsigned short f2bf(float f) {
  union { float f; unsigned u; } v; v.f = f;
  unsigned r = v.u + 0x7fffu + ((v.u >> 16) & 1u);
  return (unsigned short)(r >> 16);
}
__device__ __forceinline__ float bf2f(unsigned short u) {
  union { unsigned u; float f; } v; v.u = ((unsigned)u) << 16;
  return v.f;
}
__device__ __forceinline__ float sigf(float x) {
  return __builtin_amdgcn_rcpf(1.0f + __expf(-x));
}

// ---------------- prep: weight fragments + Q2 ----------------
__global__ __launch_bounds__(256)
void prep_weights(const float* __restrict__ W1, const float* __restrict__ W2,
                  unsigned short* __restrict__ wcf, unsigned short* __restrict__ w2f,
                  float* __restrict__ Q2)
{
  int g = blockIdx.x * 256 + threadIdx.x;
  if (g < 8192) {
    // Wc frag: c in [0,16), s in [0,8), l in [0,64)
    int c = g >> 9, s = (g >> 6) & 7, l = g & 63;
    int col = 16 * c + (l & 15);
#pragma unroll
    for (int j = 0; j < 8; ++j) {
      int k = 32 * s + 8 * (l >> 4) + j;
      float v = W1[(256 + k) * H1_ + col];          // W1c (k<128) or W1d (k>=128)
      if (k < 128) v += W1[k * H1_ + col];          // + W1a
      wcf[(size_t)g * 8 + j] = f2bf(v);
    }
  } else if (g < 12288) {
    int g2 = g - 8192;                              // c in [0,8), s in [0,8), l
    int c = g2 >> 9, s = (g2 >> 6) & 7, l = g2 & 63;
    int col = 16 * c + (l & 15);
#pragma unroll
    for (int j = 0; j < 8; ++j) {
      int k = 32 * s + 8 * (l >> 4) + j;
      w2f[(size_t)g2 * 8 + j] = f2bf(W2[k * H2_ + col]);
    }
  } else {
    int g3 = g - 12288;                             // 8192 float4 tasks over 128x256
    int e = g3 * 4;
    int d = e >> 8, h = e & 255;
#pragma unroll
    for (int j = 0; j < 4; ++j)
      Q2[e + j] = W1[(128 + d) * H1_ + h + j] - W1[(256 + d) * H1_ + h + j];
  }
}

// ---------------- prep: qb[b][h] = b1[h] + q[b] @ Q2 ----------------
__global__ __launch_bounds__(256)
void qb_prep(const float* __restrict__ query, const float* __restrict__ b1,
             const float* __restrict__ Q2, float* __restrict__ qb)
{
  __shared__ float q8[8 * 128];
  int b0 = blockIdx.x * 8;
  int tid = threadIdx.x;
  {
    const float4 v = *(const float4*)(query + (size_t)b0 * 128 + tid * 4);
    *(float4*)(q8 + tid * 4) = v;
  }
  __syncthreads();
  int h = tid;
  float acc[8];
#pragma unroll
  for (int j = 0; j < 8; ++j) acc[j] = b1[h];
  for (int d = 0; d < 128; ++d) {
    float w = Q2[d * 256 + h];
#pragma unroll
    for (int j = 0; j < 8; ++j) acc[j] += q8[j * 128 + d] * w;
  }
#pragma unroll
  for (int j = 0; j < 8; ++j) qb[(size_t)(b0 + j) * 256 + h] = acc[j];
}

// ---------------- main ----------------
__global__ __launch_bounds__(512, 2)
void attn_main(const float* __restrict__ query, const float* __restrict__ keys,
               const int* __restrict__ mask,
               const unsigned short* __restrict__ wcf,
               const unsigned short* __restrict__ w2f,
               const float* __restrict__ qb_ws,
               const float* __restrict__ b2, const float* __restrict__ W3,
               const float* __restrict__ b3, float* __restrict__ out)
{
  __shared__ __align__(16) unsigned short Xc[64 * 256];   // 32KB swizzled
  __shared__ __align__(16) unsigned short H1c[64 * 256];  // 32KB swizzled
  __shared__ float qL[128];
  __shared__ float qbL[256];
  __shared__ float scorep[64 * 4];
  __shared__ float ebuf[64];
  __shared__ float numred[4][128];
  __shared__ float denred[4];

  const int b = blockIdx.x;
  const int tid = threadIdx.x;
  const int lane = tid & 63;
  const int wid = tid >> 6;

  if (tid < 128) qL[tid] = query[(size_t)b * 128 + tid];
  if (tid < 256) qbL[tid] = qb_ws[(size_t)b * 256 + tid];

  // layer-2 tile assignment: 2 rows x 2 cols per wave
  const int c0 = wid & 3, c1 = c0 + 4;
  const int r0 = (wid >> 2) * 2, r1 = r0 + 1;
  const float b2v0 = b2[c0 * 16 + (lane & 15)];
  const float b2v1 = b2[c1 * 16 + (lane & 15)];
  const float w3v0 = W3[c0 * 16 + (lane & 15)];
  const float w3v1 = W3[c1 * 16 + (lane & 15)];
  const float b3v = b3[0];

  float numacc = 0.0f, denacc = 0.0f;
  const int rg = tid >> 7;          // row-group 0..3 (uniform per wave)
  const int dcol = tid & 127;       // output d

  __syncthreads();

  for (int ch = 0; ch < 4; ++ch) {
    const int base = ch * 64;
    const int rem = T_ - base;                 // 64,64,64,8
    const int nrt = (rem >= 64) ? 4 : ((rem + 15) >> 4);
    const int valid = (rem < 64) ? rem : 64;

    __syncthreads();  // Xc free from previous accum phase

    // ---- phase 1: stage X = [k, q*k] (bf16, swizzled) ----
#pragma unroll
    for (int qq = 0; qq < 2; ++qq) {
      int p = tid * 2 + qq;
      int row = p >> 4, c = p & 15;
      int t = base + row;
      float4 k0 = {0,0,0,0}, k1 = {0,0,0,0};
      if (t < T_) {
        const float* kp = keys + ((size_t)b * T_ + t) * 128 + 8 * c;
        k0 = *(const float4*)kp;
        k1 = *(const float4*)(kp + 4);
      }
      float kv[8] = {k0.x,k0.y,k0.z,k0.w,k1.x,k1.y,k1.z,k1.w};
      s16x8 xk, xq;
#pragma unroll
      for (int j = 0; j < 8; ++j) {
        xk[j] = (short)f2bf(kv[j]);
        xq[j] = (short)f2bf(kv[j] * qL[8 * c + j]);
      }
      int sw = (row & 7) << 3;
      *(s16x8*)&Xc[(row * 256 + 8 * c) ^ sw]       = xk;
      *(s16x8*)&Xc[(row * 256 + 128 + 8 * c) ^ sw] = xq;
    }
    __syncthreads();

    // ---- layer 1: h1 = sig(X @ Wc + qb); wave owns cols {wid, wid+8} ----
    {
      s16x8 Bf0[8], Bf1[8];
#pragma unroll
      for (int s = 0; s < 8; ++s) {
        Bf0[s] = *(const s16x8*)(wcf + ((size_t)(wid * 8 + s) * 64 + lane) * 8);
        Bf1[s] = *(const s16x8*)(wcf + ((size_t)((wid + 8) * 8 + s) * 64 + lane) * 8);
      }
      const float qb0 = qbL[wid * 16 + (lane & 15)];
      const float qb1 = qbL[(wid + 8) * 16 + (lane & 15)];
      const int asw = (lane & 7) << 3;
      for (int rt = 0; rt < nrt; ++rt) {
        const int abase = (rt * 16 + (lane & 15)) * 256 + (lane >> 4) * 8;
        f32x4 a0 = {0,0,0,0}, a1 = {0,0,0,0};
#pragma unroll
        for (int s = 0; s < 8; ++s) {
          s16x8 Af = *(const s16x8*)&Xc[(abase + s * 32) ^ asw];
          a0 = __builtin_amdgcn_mfma_f32_16x16x32_bf16(Af, Bf0[s], a0, 0, 0, 0);
          a1 = __builtin_amdgcn_mfma_f32_16x16x32_bf16(Af, Bf1[s], a1, 0, 0, 0);
        }
#pragma unroll
        for (int i = 0; i < 4; ++i) {
          int row = rt * 16 + (lane >> 4) * 4 + i;
          int sw = (row & 7) << 3;
          H1c[(row * 256 + wid * 16 + (lane & 15)) ^ sw]       = f2bf(sigf(a0[i] + qb0));
          H1c[(row * 256 + (wid + 8) * 16 + (lane & 15)) ^ sw] = f2bf(sigf(a1[i] + qb1));
        }
      }
    }
    __syncthreads();

    // ---- layer 2 + layer 3 partials: wave owns rows {r0,r1} x cols {c0,c1} ----
    if (r0 * 16 < valid) {
      s16x8 Bc0[8], Bc1[8];
#pragma unroll
      for (int s = 0; s < 8; ++s) {
        Bc0[s] = *(const s16x8*)(w2f + ((size_t)(c0 * 8 + s) * 64 + lane) * 8);
        Bc1[s] = *(const s16x8*)(w2f + ((size_t)(c1 * 8 + s) * 64 + lane) * 8);
      }
      const int asw = (lane & 7) << 3;
      const int ab0 = (r0 * 16 + (lane & 15)) * 256 + (lane >> 4) * 8;
      const int ab1 = (r1 * 16 + (lane & 15)) * 256 + (lane >> 4) * 8;
      f32x4 a00 = {0,0,0,0}, a01 = {0,0,0,0}, a10 = {0,0,0,0}, a11 = {0,0,0,0};
#pragma unroll
      for (int s = 0; s < 8; ++s) {
        s16x8 A0 = *(const s16x8*)&H1c[(ab0 + s * 32) ^ asw];
        s16x8 A1 = *(const s16x8*)&H1c[(ab1 + s * 32) ^ asw];
        a00 = __builtin_amdgcn_mfma_f32_16x16x32_bf16(A0, Bc0[s], a00, 0, 0, 0);
        a01 = __builtin_amdgcn_mfma_f32_16x16x32_bf16(A0, Bc1[s], a01, 0, 0, 0);
        a10 = __builtin_amdgcn_mfma_f32_16x16x32_bf16(A1, Bc0[s], a10, 0, 0, 0);
        a11 = __builtin_amdgcn_mfma_f32_16x16x32_bf16(A1, Bc1[s], a11, 0, 0, 0);
      }
      // p = sig(.)*w3, pre-sum the two col-blocks, then 16-lane reduce
      float p0[4], p1[4];
#pragma unroll
      for (int i = 0; i < 4; ++i) {
        p0[i] = sigf(a00[i] + b2v0) * w3v0 + sigf(a01[i] + b2v1) * w3v1;
        p1[i] = sigf(a10[i] + b2v0) * w3v0 + sigf(a11[i] + b2v1) * w3v1;
      }
#pragma unroll
      for (int m = 1; m <= 8; m <<= 1)
#pragma unroll
        for (int i = 0; i < 4; ++i) {
          p0[i] += __shfl_xor(p0[i], m);
          p1[i] += __shfl_xor(p1[i], m);
        }
      if ((lane & 15) == 0) {
#pragma unroll
        for (int i = 0; i < 4; ++i) {
          int rr0 = r0 * 16 + (lane >> 4) * 4 + i;
          int rr1 = r1 * 16 + (lane >> 4) * 4 + i;
          scorep[rr0 * 4 + c0] = p0[i];
          scorep[rr1 * 4 + c0] = p1[i];
        }
      }
    }
    __syncthreads();

    // ---- finalize score -> e ----
    if (tid < 64) {
      int r = tid, t = base + r;
      float e = 0.0f;
      if (t < T_) {
        float s4 = scorep[r * 4] + scorep[r * 4 + 1] + scorep[r * 4 + 2] + scorep[r * 4 + 3];
        if (mask[(size_t)b * T_ + t] == 1)
          e = __expf(sigf(s4 + b3v));
      }
      ebuf[r] = e;
    }
    __syncthreads();

    // ---- accumulate num/den from staged keys ----
#pragma unroll 4
    for (int rr = 0; rr < 16; ++rr) {
      int row = rg * 16 + rr;
      float ev = ebuf[row];              // wave-uniform
      if (ev != 0.0f) {
        denacc += ev;
        numacc += ev * bf2f(Xc[(row * 256 + dcol) ^ ((row & 7) << 3)]);
      }
    }
  }

  // ---- final reduce across the 4 row-groups ----
  __syncthreads();
  numred[rg][dcol] = numacc;
  if ((tid & 127) == 0) denred[rg] = denacc;
  __syncthreads();
  if (tid < 128) {
    float num = numred[0][tid] + numred[1][tid] + numred[2][tid] + numred[3][tid];
    float den = denred[0] + denred[1] + denred[2] + denred[3];
    out[(size_t)b * 128 + tid] = num / den;
  }
}

extern "C" void kernel_launch(void* const* d_in, const int* in_sizes, int n_in,
                              void* d_out, int out_size, void* d_ws, size_t ws_size,
                              hipStream_t stream) {
  const float* query = (const float*)d_in[0];
  const float* keys  = (const float*)d_in[1];
  const int*   mask  = (const int*)  d_in[2];
  const float* W1    = (const float*)d_in[3];
  const float* b1    = (const float*)d_in[4];
  const float* W2    = (const float*)d_in[5];
  const float* b2    = (const float*)d_in[6];
  const float* W3    = (const float*)d_in[7];
  const float* b3    = (const float*)d_in[8];
  float* out = (float*)d_out;

  char* ws = (char*)d_ws;
  unsigned short* wcf = (unsigned short*)(ws + WS_WCF);
  unsigned short* w2f = (unsigned short*)(ws + WS_W2F);
  float*          Q2  = (float*)(ws + WS_Q2);
  float*          qb  = (float*)(ws + WS_QB);

  prep_weights<<<80, 256, 0, stream>>>(W1, W2, wcf, w2f, Q2);
  qb_prep<<<256, 256, 0, stream>>>(query, b1, Q2, qb);
  attn_main<<<B_, 512, 0, stream>>>(query, keys, mask, wcf, w2f, qb,
                                    b2, W3, b3, out);
}